// Round 1
// baseline (9048.264 us; speedup 1.0000x reference)
//
#include <hip/hip_runtime.h>
#include <hip/hip_bf16.h>
#include <hip/hip_cooperative_groups.h>
#include <math.h>

namespace cg = cooperative_groups;

typedef __hip_bfloat16 bf16;
typedef short bf16x8 __attribute__((ext_vector_type(8)));   // 8 bf16 = 4 VGPRs
typedef float f32x4 __attribute__((ext_vector_type(4)));

__device__ __forceinline__ float sigf(float x) { return 1.f / (1.f + expf(-x)); }

template<typename T> __device__ __forceinline__ T cvt_out(float v);
template<> __device__ __forceinline__ float cvt_out<float>(float v) { return v; }
template<> __device__ __forceinline__ bf16  cvt_out<bf16>(float v)  { return __float2bfloat16(v); }

__device__ __forceinline__ unsigned short f2bu(float x) {
  bf16 b = __float2bfloat16(x);
  return *reinterpret_cast<unsigned short*>(&b);
}
__device__ __forceinline__ float bu2f(unsigned short u) {
  unsigned int x = ((unsigned int)u) << 16;
  return __uint_as_float(x);
}

// async global->LDS, 16B per lane. LDS dest must be wave-uniform-base + lane*16.
__device__ __forceinline__ void load_lds16(const void* g, void* l) {
  __builtin_amdgcn_global_load_lds(
      (const __attribute__((address_space(1))) unsigned int*)g,
      (__attribute__((address_space(3))) unsigned int*)l,
      16, 0, 0);
}

// ---------------- patch extraction: X[512,3,32,32] -> v_fw[64,512,48] f32 ----------------
__global__ void patch_kernel(const float* __restrict__ X, float* __restrict__ v) {
  int idx = blockIdx.x * 256 + threadIdx.x;
  int k = idx % 48;
  int b = (idx / 48) % 512;
  int t = idx / (48 * 512);
  int c = k >> 4, r = (k >> 2) & 3, s = k & 3;
  int ph = t & 7, pw = t >> 3;
  v[idx] = X[((b * 3 + c) * 32 + ph * 4 + r) * 32 + pw * 4 + s];
}

// ---------------- fp32 -> bf16 convert (x4 vectorized) ----------------
__global__ __launch_bounds__(256) void cvt_f32_bf16_k(const float* __restrict__ in,
                                                      bf16* __restrict__ out, size_t n4) {
  size_t i = (size_t)blockIdx.x * 256 + threadIdx.x;
  if (i >= n4) return;
  float4 v = ((const float4*)in)[i];
  ushort4 o;
  o.x = f2bu(v.x); o.y = f2bu(v.y); o.z = f2bu(v.z); o.w = f2bu(v.w);
  ((ushort4*)out)[i] = o;
}

// ---------------- legacy fp32 GEMM (only for xg1/xg2, K=48): C = A@W^T + b1 + b2 ----------------
template<typename OutT, bool RELU>
__global__ __launch_bounds__(256) void gemm_nt(
    const float* __restrict__ A, const float* __restrict__ W,
    const float* __restrict__ b1, const float* __restrict__ b2,
    OutT* __restrict__ C, int M, int N, int K, int ldc) {
  __shared__ float As[16][68];
  __shared__ float Ws[16][68];
  int tid = threadIdx.x;
  int tx = tid & 15, ty = tid >> 4;
  int m0 = blockIdx.y << 6, n0 = blockIdx.x << 6;
  const float* Ap = A + (size_t)m0 * K;
  const float* Wp = W + (size_t)n0 * K;
  float acc[4][4] = {};
  for (int k0 = 0; k0 < K; k0 += 16) {
#pragma unroll
    for (int i = 0; i < 4; i++) {
      int idx = tid + (i << 8);
      int row = idx >> 4, col = idx & 15;
      As[col][row] = Ap[(size_t)row * K + k0 + col];
      Ws[col][row] = Wp[(size_t)row * K + k0 + col];
    }
    __syncthreads();
#pragma unroll
    for (int kk = 0; kk < 16; kk++) {
      float4 av = *(const float4*)&As[kk][ty << 2];
      float4 wv = *(const float4*)&Ws[kk][tx << 2];
      float a[4] = {av.x, av.y, av.z, av.w};
      float w[4] = {wv.x, wv.y, wv.z, wv.w};
#pragma unroll
      for (int i = 0; i < 4; i++)
#pragma unroll
        for (int j = 0; j < 4; j++) acc[i][j] += a[i] * w[j];
    }
    __syncthreads();
  }
#pragma unroll
  for (int i = 0; i < 4; i++) {
    int m = m0 + (ty << 2) + i;
#pragma unroll
    for (int j = 0; j < 4; j++) {
      int n = n0 + (tx << 2) + j;
      float v = acc[i][j];
      if (b1) v += b1[n];
      if (b2) v += b2[n];
      if (RELU) v = fmaxf(v, 0.f);
      C[(size_t)m * ldc + n] = cvt_out<OutT>(v);
    }
  }
}

// ---------------- bf16 MFMA GEMM (NT): C[M,N] = A[M,K] @ W[N,K]^T (+bias) ----------------
template<typename OutT, bool RELU, bool SPLITK>
__global__ __launch_bounds__(256) void gemm_mfma(
    const bf16* __restrict__ A, const bf16* __restrict__ W,
    const float* __restrict__ b1, const float* __restrict__ b2,
    OutT* __restrict__ C, int M, int N, int K, int ldc, int ksplit) {
  __shared__ __align__(16) short As[128 * 32];
  __shared__ __align__(16) short Ws[128 * 32];
  int tid = threadIdx.x;
  int m0 = blockIdx.y << 7, n0 = blockIdx.x << 7;
  int kb = SPLITK ? blockIdx.z * ksplit : 0;
  int ke = SPLITK ? kb + ksplit : K;
  int w = tid >> 6, lane = tid & 63;
  int wm = (w >> 1) << 6, wn = (w & 1) << 6;
  int lm = lane & 15, quad = lane >> 4;
  f32x4 acc[4][4];
  f32x4 z4 = {0.f, 0.f, 0.f, 0.f};
#pragma unroll
  for (int i = 0; i < 4; i++)
#pragma unroll
    for (int j = 0; j < 4; j++) acc[i][j] = z4;

  int srow = tid >> 2;          // 0..63
  int soff = (tid & 3) * 8;     // bf16 elems within K-chunk
  const bf16* Ab  = A + (size_t)(m0 + srow) * K + kb + soff;
  const bf16* Ab2 = Ab + (size_t)64 * K;
  const bf16* Wb  = W + (size_t)(n0 + srow) * K + kb + soff;
  const bf16* Wb2 = Wb + (size_t)64 * K;
  short* AL  = &As[(size_t)tid * 8];
  short* AL2 = &As[(size_t)(tid + 256) * 8];
  short* WL  = &Ws[(size_t)tid * 8];
  short* WL2 = &Ws[(size_t)(tid + 256) * 8];

  for (int k0 = kb; k0 < ke; k0 += 32) {
    load_lds16(Ab, AL);  load_lds16(Ab2, AL2);
    load_lds16(Wb, WL);  load_lds16(Wb2, WL2);
    Ab += 32; Ab2 += 32; Wb += 32; Wb2 += 32;
    __syncthreads();   // vmcnt(0) drain -> LDS valid
    bf16x8 af[4], wf[4];
#pragma unroll
    for (int i = 0; i < 4; i++) af[i] = *(const bf16x8*)&As[(wm + i * 16 + lm) * 32 + quad * 8];
#pragma unroll
    for (int j = 0; j < 4; j++) wf[j] = *(const bf16x8*)&Ws[(wn + j * 16 + lm) * 32 + quad * 8];
#pragma unroll
    for (int i = 0; i < 4; i++)
#pragma unroll
      for (int j = 0; j < 4; j++)
        acc[i][j] = __builtin_amdgcn_mfma_f32_16x16x32_bf16(af[i], wf[j], acc[i][j], 0, 0, 0);
    __syncthreads();   // protect LDS before next overwrite
  }

  if (SPLITK) {
    float* P = (float*)C + (size_t)blockIdx.z * M * N;
#pragma unroll
    for (int i = 0; i < 4; i++)
#pragma unroll
      for (int j = 0; j < 4; j++) {
        int col = n0 + wn + j * 16 + lm;
        int rowb = m0 + wm + i * 16 + quad * 4;
#pragma unroll
        for (int r = 0; r < 4; r++)
          P[(size_t)(rowb + r) * N + col] = acc[i][j][r];
      }
  } else {
#pragma unroll
    for (int i = 0; i < 4; i++)
#pragma unroll
      for (int j = 0; j < 4; j++) {
        int col = n0 + wn + j * 16 + lm;
        int rowb = m0 + wm + i * 16 + quad * 4;
        float bias = (b1 ? b1[col] : 0.f) + (b2 ? b2[col] : 0.f);
#pragma unroll
        for (int r = 0; r < 4; r++) {
          float v = acc[i][j][r] + bias;
          if (RELU) v = fmaxf(v, 0.f);
          C[(size_t)(rowb + r) * ldc + col] = cvt_out<OutT>(v);
        }
      }
  }
}

// ---------------- split-K reduce + bias + relu ----------------
__global__ __launch_bounds__(256) void splitk_reduce(const float* __restrict__ P,
                                                     const float* __restrict__ bias,
                                                     float* __restrict__ out,
                                                     int MN, int N, int ldc, int nz) {
  int i = blockIdx.x * 256 + threadIdx.x;
  if (i >= MN) return;
  int m = i / N, n = i - m * N;
  float s = bias[n];
  for (int z = 0; z < nz; z++) s += P[(size_t)z * MN + i];
  out[(size_t)m * ldc + n] = fmaxf(s, 0.f);
}

// ---------------- persistent cooperative LSTM scan (64 steps, 2 LSTMs) ----------------
// grid (10 j-tiles, 8 r-tiles, 2 lstm) = 160 blocks, 256 thr = 4 waves (wave = gate).
// Whh fragment-packed resident in LDS (80 KB, loaded once). Per step: stage h hi/lo
// (double-buffered, 1 barrier/K-chunk), 16 MFMA/chunk, pointwise epilogue, grid.sync().
struct ScanArgs {
  const bf16 *xgF, *xgR, *WhhA, *WhhB;
  bf16 *h0hiA, *h0loA, *h1hiA, *h1loA; float* cA;
  bf16 *h0hiB, *h0loB, *h1hiB, *h1loB; float* cB;
  bf16 *outA, *outB;
  int ldo; size_t ostep;
};

__global__ __launch_bounds__(256, 1) void lstm_scan_mfma(ScanArgs a) {
  int lst = blockIdx.z;
  const bf16* Whh = lst ? a.WhhB : a.WhhA;
  bf16* h0hi = lst ? a.h0hiB : a.h0hiA;
  bf16* h0lo = lst ? a.h0loB : a.h0loA;
  bf16* h1hi = lst ? a.h1hiB : a.h1hiA;
  bf16* h1lo = lst ? a.h1loB : a.h1loA;
  float* c   = lst ? a.cB : a.cA;
  bf16* ob   = lst ? a.outB : a.outA;
  int j0 = blockIdx.x << 5;   // hidden tile base (32 wide)
  int r0 = blockIdx.y << 6;   // batch tile base (64 rows)

  __shared__ __align__(16) short Bf[40960];     // 80 KB: Whh slice, fragment-packed
  __shared__ __align__(16) short Ah[2][2048];   // h_hi chunk, double-buffered (4+4 KB)
  __shared__ __align__(16) short Al[2][2048];   // h_lo chunk
  __shared__ float G[64 * 129];                 // gate preacts (pad 129)

  int tid = threadIdx.x;
  int g = tid >> 6, lane = tid & 63;
  int lm = lane & 15, quad = lane >> 4;
  int l8 = lane << 3;

  // --- persistent Whh fragments: entry ((kk*4+g2)*2+j)*64+lane = 8 bf16 ---
  // fragment (g2,j,lane): Whh row g2*320 + j0 + j*16 + (lane&15), cols kk*32+(lane>>4)*8..
  for (int idx = tid; idx < 5120; idx += 256) {
    int ln = idx & 63;
    int j  = (idx >> 6) & 1;
    int g2 = (idx >> 7) & 3;
    int kk = idx >> 9;
    int grow = g2 * 320 + j0 + (j << 4) + (ln & 15);
    int k    = (kk << 5) + ((ln >> 4) << 3);
    *(bf16x8*)&Bf[(size_t)idx * 8] = *(const bf16x8*)&Whh[(size_t)grow * 320 + k];
  }

  int srow = tid >> 2;           // 0..63
  int soff = (tid & 3) * 8;
  size_t hbase = (size_t)(r0 + srow) * 320 + soff;
  short* AhL[2] = { &Ah[0][tid * 8], &Ah[1][tid * 8] };
  short* AlL[2] = { &Al[0][tid * 8], &Al[1][tid * 8] };

  int jb = (tid & 3) * 8;        // epilogue: row srow, 8 hidden cols at j0+jb
  int r = r0 + srow;
  size_t sb = (size_t)r * 320 + j0 + jb;
  size_t obase = (size_t)r * a.ldo + j0 + jb;

  cg::grid_group grid = cg::this_grid();
  __syncthreads();   // Bf visible to all waves before first use

  for (int t = 0; t < 64; ++t) {
    const bf16* hih = (t & 1) ? h1hi : h0hi;
    const bf16* hil = (t & 1) ? h1lo : h0lo;
    bf16* hoh = (t & 1) ? h0hi : h1hi;
    bf16* hol = (t & 1) ? h0lo : h1lo;
    const bf16* xg_t = lst ? a.xgR + (size_t)(63 - t) * 655360
                           : a.xgF + (size_t)t * 655360;

    f32x4 acc[4][2];
    f32x4 z4 = {0.f, 0.f, 0.f, 0.f};
#pragma unroll
    for (int i = 0; i < 4; i++) { acc[i][0] = z4; acc[i][1] = z4; }

    // K-loop: double-buffered h staging, one barrier per chunk
    load_lds16(hih + hbase, AhL[0]);
    load_lds16(hil + hbase, AlL[0]);
    __syncthreads();
    int cur = 0;
    for (int kk = 0; kk < 10; ++kk) {
      if (kk < 9) {
        load_lds16(hih + hbase + (kk + 1) * 32, AhL[cur ^ 1]);
        load_lds16(hil + hbase + (kk + 1) * 32, AlL[cur ^ 1]);
      }
      bf16x8 ah[4], alv[4], bv[2];
#pragma unroll
      for (int i = 0; i < 4; i++) {
        ah[i]  = *(const bf16x8*)&Ah[cur][(i * 16 + lm) * 32 + quad * 8];
        alv[i] = *(const bf16x8*)&Al[cur][(i * 16 + lm) * 32 + quad * 8];
      }
#pragma unroll
      for (int j = 0; j < 2; j++)
        bv[j] = *(const bf16x8*)&Bf[(size_t)((kk * 4 + g) * 2 + j) * 512 + l8];
#pragma unroll
      for (int i = 0; i < 4; i++)
#pragma unroll
        for (int j = 0; j < 2; j++) {
          acc[i][j] = __builtin_amdgcn_mfma_f32_16x16x32_bf16(ah[i],  bv[j], acc[i][j], 0, 0, 0);
          acc[i][j] = __builtin_amdgcn_mfma_f32_16x16x32_bf16(alv[i], bv[j], acc[i][j], 0, 0, 0);
        }
      __syncthreads();   // drains prefetch vmcnt + protects cur^1 overwrite
      cur ^= 1;
    }

    // scatter gate preacts to LDS
#pragma unroll
    for (int i = 0; i < 4; i++)
#pragma unroll
      for (int j = 0; j < 2; j++)
#pragma unroll
        for (int rr = 0; rr < 4; rr++)
          G[(i * 16 + quad * 4 + rr) * 129 + g * 32 + (j << 4) + lm] = acc[i][j][rr];
    __syncthreads();

    // pointwise: row srow, 8 consecutive hidden cols; vectorized xg/c/h IO
    float pre[4][8];
    const bf16* xgrow = xg_t + (size_t)r * 1280 + j0 + jb;
#pragma unroll
    for (int g2 = 0; g2 < 4; g2++) {
      bf16x8 xv = *(const bf16x8*)&xgrow[g2 * 320];
#pragma unroll
      for (int q = 0; q < 8; q++)
        pre[g2][q] = G[srow * 129 + g2 * 32 + jb + q] + bu2f((unsigned short)xv[q]);
    }
    float cc[8];
    *(float4*)&cc[0] = *(const float4*)&c[sb];
    *(float4*)&cc[4] = *(const float4*)&c[sb + 4];
    bf16x8 vhi, vlo;
#pragma unroll
    for (int q = 0; q < 8; q++) {
      float iv = sigf(pre[0][q]), fv = sigf(pre[1][q]);
      float gv = tanhf(pre[2][q]), ov = sigf(pre[3][q]);
      float cn = fv * cc[q] + iv * gv;
      float hn = ov * tanhf(cn);
      cc[q] = cn;
      unsigned short hu = f2bu(hn);
      vhi[q] = (short)hu;
      vlo[q] = (short)f2bu(hn - bu2f(hu));
    }
    *(float4*)&c[sb]     = *(float4*)&cc[0];
    *(float4*)&c[sb + 4] = *(float4*)&cc[4];
    *(bf16x8*)&hoh[sb] = vhi;
    *(bf16x8*)&hol[sb] = vlo;
    *(bf16x8*)&ob[(size_t)t * a.ostep + obase] = vhi;

    if (t < 63) {
      __threadfence();   // h writes device-visible before cross-block consumption
      grid.sync();
    }
  }
}

// ---------------- conv1 (3x3) + relu + maxpool2 fused ----------------
__global__ __launch_bounds__(256) void conv1_pool(
    const float* __restrict__ X, const float* __restrict__ w,
    const float* __restrict__ bias, float* __restrict__ pool) {
  int b = blockIdx.x;
  __shared__ float Xs[3 * 32 * 32];
  __shared__ float Wl[128 * 27];
  __shared__ float Bl[128];
  int tid = threadIdx.x;
  for (int i = tid; i < 3072; i += 256) Xs[i] = X[(size_t)b * 3072 + i];
  for (int i = tid; i < 3456; i += 256) Wl[i] = w[i];
  if (tid < 128) Bl[tid] = bias[tid];
  __syncthreads();
  int oc = tid & 127, half = tid >> 7;
  float wr[27];
#pragma unroll
  for (int q = 0; q < 27; q++) wr[q] = Wl[oc * 27 + q];
  float bv = Bl[oc];
  for (int p = half; p < 225; p += 2) {
    int i = p / 15, j = p % 15;
    float mx = -3.4e38f;
#pragma unroll
    for (int dy = 0; dy < 2; dy++)
#pragma unroll
      for (int dx = 0; dx < 2; dx++) {
        float s = bv;
        int rb = 2 * i + dy, cb = 2 * j + dx;
#pragma unroll
        for (int cc = 0; cc < 3; cc++)
#pragma unroll
          for (int kr = 0; kr < 3; kr++)
#pragma unroll
            for (int kc = 0; kc < 3; kc++)
              s += wr[cc * 9 + kr * 3 + kc] * Xs[cc * 1024 + (rb + kr) * 32 + cb + kc];
        mx = fmaxf(mx, s);
      }
    pool[((size_t)(b * 128 + oc)) * 225 + p] = fmaxf(mx, 0.f);
  }
}

// ---------------- batchnorm stats -> fold to a*x+s ----------------
__global__ void bn_stats(const float* __restrict__ x, int C, int per, int B,
                         const float* __restrict__ g, const float* __restrict__ bb,
                         float* __restrict__ a, float* __restrict__ s) {
  int c = blockIdx.x;
  int n = B * per;
  float sum = 0.f, sq = 0.f;
  for (int i = threadIdx.x; i < n; i += 256) {
    int b = i / per, p = i - b * per;
    float v = x[((size_t)b * C + c) * per + p];
    sum += v; sq += v * v;
  }
  __shared__ float S1[256], S2[256];
  S1[threadIdx.x] = sum; S2[threadIdx.x] = sq;
  __syncthreads();
  for (int off = 128; off > 0; off >>= 1) {
    if (threadIdx.x < off) { S1[threadIdx.x] += S1[threadIdx.x + off]; S2[threadIdx.x] += S2[threadIdx.x + off]; }
    __syncthreads();
  }
  if (threadIdx.x == 0) {
    float m = S1[0] / n;
    float var = S2[0] / n - m * m;
    float av = g[c] * rsqrtf(var + 1e-5f);
    a[c] = av; s[c] = bb[c] - m * av;
  }
}

__global__ void bn_apply_bf16(const float* __restrict__ x, bf16* __restrict__ y,
                              const float* __restrict__ a, const float* __restrict__ s,
                              int per, int C, size_t total) {
  size_t i = (size_t)blockIdx.x * 256 + threadIdx.x;
  if (i < total) {
    int ch = (int)((i / per) % C);
    y[i] = __float2bfloat16(a[ch] * x[i] + s[ch]);
  }
}

// ---------------- conv2 (4x4, 128->48), bn1 on load, relu on store ----------------
__global__ __launch_bounds__(192) void conv2_kernel(
    const float* __restrict__ pool, const float* __restrict__ w,
    const float* __restrict__ bias, const float* __restrict__ a1,
    const float* __restrict__ s1, float* __restrict__ out) {
  int rg = blockIdx.x, b = blockIdx.y;
  int r0 = rg * 4;
  __shared__ float L[128 * 7 * 15];
  int tid = threadIdx.x;
#pragma unroll
  for (int i = 0; i < 70; i++) {
    int idx = tid + i * 192;
    int c = idx / 105, rem = idx % 105;
    int r = rem / 15, col = rem % 15;
    L[idx] = pool[((size_t)(b * 128 + c)) * 225 + (r0 + r) * 15 + col] * a1[c] + s1[c];
  }
  __syncthreads();
  int oc = tid % 48, orow = tid / 48;
  float acc[12];
  float bv = bias[oc];
#pragma unroll
  for (int j = 0; j < 12; j++) acc[j] = bv;
  for (int c = 0; c < 128; c++) {
#pragma unroll
    for (int kr = 0; kr < 4; kr++) {
      float v[15];
#pragma unroll
      for (int q = 0; q < 15; q++) v[q] = L[(c * 7 + orow + kr) * 15 + q];
      const float* wp = &w[((size_t)(oc * 128 + c)) * 16 + kr * 4];
#pragma unroll
      for (int kc = 0; kc < 4; kc++) {
        float wv = wp[kc];
#pragma unroll
        for (int j = 0; j < 12; j++) acc[j] += wv * v[j + kc];
      }
    }
  }
  float* op = &out[((size_t)(b * 48 + oc)) * 144 + (r0 + orow) * 12];
#pragma unroll
  for (int j = 0; j < 12; j++) op[j] = fmaxf(acc[j], 0.f);
}

// ---------------- fc + log_softmax ----------------
__global__ __launch_bounds__(64) void fc_logsoftmax(
    const float* __restrict__ A, const float* __restrict__ W,
    const float* __restrict__ bias, float* __restrict__ out) {
  int b = blockIdx.x, lane = threadIdx.x;
  float acc[10] = {};
  for (int k = lane; k < 4096; k += 64) {
    float x = A[(size_t)b * 4096 + k];
#pragma unroll
    for (int o = 0; o < 10; o++) acc[o] += x * W[o * 4096 + k];
  }
#pragma unroll
  for (int o = 0; o < 10; o++)
    for (int off = 32; off > 0; off >>= 1) acc[o] += __shfl_down(acc[o], off);
  if (lane == 0) {
    float l[10];
    float m = -3.4e38f;
#pragma unroll
    for (int o = 0; o < 10; o++) { l[o] = acc[o] + bias[o]; m = fmaxf(m, l[o]); }
    float se = 0.f;
#pragma unroll
    for (int o = 0; o < 10; o++) se += expf(l[o] - m);
    float ls = logf(se);
#pragma unroll
    for (int o = 0; o < 10; o++) out[b * 10 + o] = l[o] - m - ls;
  }
}

__global__ void zero_k(float* __restrict__ p, size_t n) {
  size_t i = (size_t)blockIdx.x * 256 + threadIdx.x;
  if (i < n) p[i] = 0.f;
}

extern "C" void kernel_launch(void* const* d_in, const int* in_sizes, int n_in,
                              void* d_out, int out_size, void* d_ws, size_t ws_size,
                              hipStream_t stream) {
  const float* X    = (const float*)d_in[0];
  const float* c1w  = (const float*)d_in[1];
  const float* c1b  = (const float*)d_in[2];
  const float* bn1g = (const float*)d_in[3];
  const float* bn1b = (const float*)d_in[4];
  const float* c2w  = (const float*)d_in[5];
  const float* c2b  = (const float*)d_in[6];
  const float* bn2g = (const float*)d_in[7];
  const float* bn2b = (const float*)d_in[8];
  const float *Wih[4], *Whh[4], *bih[4], *bhh[4];
  for (int i = 0; i < 4; i++) {
    Wih[i] = (const float*)d_in[9 + 4 * i];
    Whh[i] = (const float*)d_in[10 + 4 * i];
    bih[i] = (const float*)d_in[11 + 4 * i];
    bhh[i] = (const float*)d_in[12 + 4 * i];
  }
  const float* d1w = (const float*)d_in[25];
  const float* d1b = (const float*)d_in[26];
  const float* d2w = (const float*)d_in[27];
  const float* d2b = (const float*)d_in[28];
  const float* fcw = (const float*)d_in[29];
  const float* fcb = (const float*)d_in[30];
  float* out = (float*)d_out;

  // ---- workspace layout (~294 MB) ----
  char* p = (char*)d_ws;
  float* v_fw = (float*)p;  p += (size_t)64 * 512 * 48 * 4;         // 6.3 MB
  char* R = p;              p += (size_t)167772160;                  // xg region (2x 83.9MB)
  bf16* xgA = (bf16*)R;
  bf16* xgB = xgA + (size_t)41943040;
  bf16* h_fw = (bf16*)p;    p += (size_t)64 * 512 * 640 * 2;         // 41.9 MB
  bf16* hfm  = (bf16*)p;    p += (size_t)512 * 40960 * 2;            // 41.9 MB
  bf16* wih3b = (bf16*)p;   p += (size_t)1280 * 640 * 2;
  bf16* wih4b = (bf16*)p;   p += (size_t)1280 * 640 * 2;
  bf16* whhb[4];
  for (int i = 0; i < 4; i++) { whhb[i] = (bf16*)p; p += (size_t)1280 * 320 * 2; }
  float* states = (float*)p; p += (size_t)3932160;                   // c (f32) + h hi/lo pp (bf16)
  float* P = (float*)p;      p += (size_t)4 * 512 * 2048 * 4;        // 16.8 MB split-K partials
  float* outcat = (float*)p; p += (size_t)512 * 4096 * 4;            // 8.4 MB
  float* bnp = (float*)p;    p += 2048;
  // conv aliases inside R (dead after dense1):
  float* pool   = (float*)R;                                         // 59.0 MB
  float* c2out  = (float*)(R + 58982400);                            // 14.2 MB
  bf16*  c2outb = (bf16*)(R + 58982400 + 14155776);                  // 7.1 MB
  bf16*  d2wb   = (bf16*)(R + 58982400 + 14155776 + 7077888);        // 28.3 MB
  bf16*  d1wb   = (bf16*)R;                                          // 167.8 MB (whole R)
  float* a1 = bnp, *s1 = bnp + 128, *a2 = bnp + 256, *s2 = bnp + 304;

  float* cA = states;
  float* cB = cA + 163840;
  bf16* hb = (bf16*)(cB + 163840);
  bf16* hA0h = hb;             bf16* hA0l = hb + 163840;
  bf16* hA1h = hb + 327680;    bf16* hA1l = hb + 491520;
  bf16* hB0h = hb + 655360;    bf16* hB0l = hb + 819200;
  bf16* hB1h = hb + 983040;    bf16* hB1l = hb + 1146880;

  // 1) patches + small weight conversions
  patch_kernel<<<6144, 256, 0, stream>>>(X, v_fw);
  for (int i = 0; i < 4; i++)
    cvt_f32_bf16_k<<<400, 256, 0, stream>>>(Whh[i], whhb[i], 102400);
  cvt_f32_bf16_k<<<800, 256, 0, stream>>>(Wih[2], wih3b, 204800);
  cvt_f32_bf16_k<<<800, 256, 0, stream>>>(Wih[3], wih4b, 204800);

  // 2) input projections for LSTM 1/2 (K=48, legacy fp32 gemm, bf16 out)
  gemm_nt<bf16, false><<<dim3(20, 512), 256, 0, stream>>>(v_fw, Wih[0], bih[0], bhh[0], xgA, 32768, 1280, 48, 1280);
  gemm_nt<bf16, false><<<dim3(20, 512), 256, 0, stream>>>(v_fw, Wih[1], bih[1], bhh[1], xgB, 32768, 1280, 48, 1280);

  // 3) phase A scan — one persistent cooperative kernel (was 64 launches)
  zero_k<<<3840, 256, 0, stream>>>(states, (size_t)983040);
  {
    ScanArgs sa;
    sa.xgF = xgA; sa.xgR = xgB; sa.WhhA = whhb[0]; sa.WhhB = whhb[1];
    sa.h0hiA = hA0h; sa.h0loA = hA0l; sa.h1hiA = hA1h; sa.h1loA = hA1l; sa.cA = cA;
    sa.h0hiB = hB0h; sa.h0loB = hB0l; sa.h1hiB = hB1h; sa.h1loB = hB1l; sa.cB = cB;
    sa.outA = h_fw; sa.outB = h_fw + 320; sa.ldo = 640; sa.ostep = 327680;
    void* ka[] = { &sa };
    hipLaunchCooperativeKernel((void*)lstm_scan_mfma, dim3(10, 8, 2), dim3(256, 1, 1), ka, 0, stream);
  }

  // 4) input projections for LSTM 3/4 (MFMA, overwrite xg region)
  gemm_mfma<bf16, false, false><<<dim3(10, 256, 1), 256, 0, stream>>>(h_fw, wih3b, bih[2], bhh[2], xgA, 32768, 1280, 640, 1280, 0);
  gemm_mfma<bf16, false, false><<<dim3(10, 256, 1), 256, 0, stream>>>(h_fw, wih4b, bih[3], bhh[3], xgB, 32768, 1280, 640, 1280, 0);

  // 5) phase B scan -> hfm
  zero_k<<<3840, 256, 0, stream>>>(states, (size_t)983040);
  {
    ScanArgs sb;
    sb.xgF = xgA; sb.xgR = xgB; sb.WhhA = whhb[2]; sb.WhhB = whhb[3];
    sb.h0hiA = hA0h; sb.h0loA = hA0l; sb.h1hiA = hA1h; sb.h1loA = hA1l; sb.cA = cA;
    sb.h0hiB = hB0h; sb.h0loB = hB0l; sb.h1hiB = hB1h; sb.h1loB = hB1l; sb.cB = cB;
    sb.outA = hfm; sb.outB = hfm + 320; sb.ldo = 40960; sb.ostep = 640;
    void* ka[] = { &sb };
    hipLaunchCooperativeKernel((void*)lstm_scan_mfma, dim3(10, 8, 2), dim3(256, 1, 1), ka, 0, stream);
  }

  // 6) dense1 (split-K=4) -> outcat[:, 0:2048]
  cvt_f32_bf16_k<<<81920, 256, 0, stream>>>(d1w, d1wb, 20971520);
  gemm_mfma<float, false, true><<<dim3(16, 4, 4), 256, 0, stream>>>(hfm, d1wb, nullptr, nullptr, P, 512, 2048, 40960, 2048, 10240);
  splitk_reduce<<<4096, 256, 0, stream>>>(P, d1b, outcat, 1048576, 2048, 4096, 4);

  // 7) conv branch (d1wb dead -> pool/c2out alias R)
  conv1_pool<<<512, 256, 0, stream>>>(X, c1w, c1b, pool);
  bn_stats<<<128, 256, 0, stream>>>(pool, 128, 225, 512, bn1g, bn1b, a1, s1);
  conv2_kernel<<<dim3(3, 512), 192, 0, stream>>>(pool, c2w, c2b, a1, s1, c2out);
  bn_stats<<<48, 256, 0, stream>>>(c2out, 48, 144, 512, bn2g, bn2b, a2, s2);
  bn_apply_bf16<<<13824, 256, 0, stream>>>(c2out, c2outb, a2, s2, 144, 48, (size_t)3538944);

  // 8) dense2 (split-K=4) -> outcat[:, 2048:4096]
  cvt_f32_bf16_k<<<13824, 256, 0, stream>>>(d2w, d2wb, 3538944);
  gemm_mfma<float, false, true><<<dim3(16, 4, 4), 256, 0, stream>>>(c2outb, d2wb, nullptr, nullptr, P, 512, 2048, 6912, 2048, 1728);
  splitk_reduce<<<4096, 256, 0, stream>>>(P, d2b, outcat + 2048, 1048576, 2048, 4096, 4);

  // 9) fc + log_softmax
  fc_logsoftmax<<<512, 64, 0, stream>>>(outcat, fcw, fcb, out);
}

// Round 2
// 6101.720 us; speedup vs baseline: 1.4829x; 1.4829x over previous
//
#include <hip/hip_runtime.h>
#include <hip/hip_bf16.h>
#include <math.h>

typedef __hip_bfloat16 bf16;
typedef short bf16x8 __attribute__((ext_vector_type(8)));   // 8 bf16 = 4 VGPRs
typedef float f32x4 __attribute__((ext_vector_type(4)));

__device__ __forceinline__ float sigf(float x) { return 1.f / (1.f + expf(-x)); }

template<typename T> __device__ __forceinline__ T cvt_out(float v);
template<> __device__ __forceinline__ float cvt_out<float>(float v) { return v; }
template<> __device__ __forceinline__ bf16  cvt_out<bf16>(float v)  { return __float2bfloat16(v); }

__device__ __forceinline__ unsigned short f2bu(float x) {
  bf16 b = __float2bfloat16(x);
  return *reinterpret_cast<unsigned short*>(&b);
}
__device__ __forceinline__ float bu2f(unsigned short u) {
  unsigned int x = ((unsigned int)u) << 16;
  return __uint_as_float(x);
}

// async global->LDS, 16B per lane. LDS dest must be wave-uniform-base + lane*16.
__device__ __forceinline__ void load_lds16(const void* g, void* l) {
  __builtin_amdgcn_global_load_lds(
      (const __attribute__((address_space(1))) unsigned int*)g,
      (__attribute__((address_space(3))) unsigned int*)l,
      16, 0, 0);
}

// ---------------- patch extraction: X[512,3,32,32] -> v_fw[64,512,48] f32 ----------------
__global__ void patch_kernel(const float* __restrict__ X, float* __restrict__ v) {
  int idx = blockIdx.x * 256 + threadIdx.x;
  int k = idx % 48;
  int b = (idx / 48) % 512;
  int t = idx / (48 * 512);
  int c = k >> 4, r = (k >> 2) & 3, s = k & 3;
  int ph = t & 7, pw = t >> 3;
  v[idx] = X[((b * 3 + c) * 32 + ph * 4 + r) * 32 + pw * 4 + s];
}

// ---------------- fp32 -> bf16 convert (x4 vectorized) ----------------
__global__ __launch_bounds__(256) void cvt_f32_bf16_k(const float* __restrict__ in,
                                                      bf16* __restrict__ out, size_t n4) {
  size_t i = (size_t)blockIdx.x * 256 + threadIdx.x;
  if (i >= n4) return;
  float4 v = ((const float4*)in)[i];
  ushort4 o;
  o.x = f2bu(v.x); o.y = f2bu(v.y); o.z = f2bu(v.z); o.w = f2bu(v.w);
  ((ushort4*)out)[i] = o;
}

// ---------------- legacy fp32 GEMM (only for xg1/xg2, K=48): C = A@W^T + b1 + b2 ----------------
template<typename OutT, bool RELU>
__global__ __launch_bounds__(256) void gemm_nt(
    const float* __restrict__ A, const float* __restrict__ W,
    const float* __restrict__ b1, const float* __restrict__ b2,
    OutT* __restrict__ C, int M, int N, int K, int ldc) {
  __shared__ float As[16][68];
  __shared__ float Ws[16][68];
  int tid = threadIdx.x;
  int tx = tid & 15, ty = tid >> 4;
  int m0 = blockIdx.y << 6, n0 = blockIdx.x << 6;
  const float* Ap = A + (size_t)m0 * K;
  const float* Wp = W + (size_t)n0 * K;
  float acc[4][4] = {};
  for (int k0 = 0; k0 < K; k0 += 16) {
#pragma unroll
    for (int i = 0; i < 4; i++) {
      int idx = tid + (i << 8);
      int row = idx >> 4, col = idx & 15;
      As[col][row] = Ap[(size_t)row * K + k0 + col];
      Ws[col][row] = Wp[(size_t)row * K + k0 + col];
    }
    __syncthreads();
#pragma unroll
    for (int kk = 0; kk < 16; kk++) {
      float4 av = *(const float4*)&As[kk][ty << 2];
      float4 wv = *(const float4*)&Ws[kk][tx << 2];
      float a[4] = {av.x, av.y, av.z, av.w};
      float w[4] = {wv.x, wv.y, wv.z, wv.w};
#pragma unroll
      for (int i = 0; i < 4; i++)
#pragma unroll
        for (int j = 0; j < 4; j++) acc[i][j] += a[i] * w[j];
    }
    __syncthreads();
  }
#pragma unroll
  for (int i = 0; i < 4; i++) {
    int m = m0 + (ty << 2) + i;
#pragma unroll
    for (int j = 0; j < 4; j++) {
      int n = n0 + (tx << 2) + j;
      float v = acc[i][j];
      if (b1) v += b1[n];
      if (b2) v += b2[n];
      if (RELU) v = fmaxf(v, 0.f);
      C[(size_t)m * ldc + n] = cvt_out<OutT>(v);
    }
  }
}

// ---------------- bf16 MFMA GEMM (NT): C[M,N] = A[M,K] @ W[N,K]^T (+bias) ----------------
template<typename OutT, bool RELU, bool SPLITK>
__global__ __launch_bounds__(256) void gemm_mfma(
    const bf16* __restrict__ A, const bf16* __restrict__ W,
    const float* __restrict__ b1, const float* __restrict__ b2,
    OutT* __restrict__ C, int M, int N, int K, int ldc, int ksplit) {
  __shared__ __align__(16) short As[128 * 32];
  __shared__ __align__(16) short Ws[128 * 32];
  int tid = threadIdx.x;
  int m0 = blockIdx.y << 7, n0 = blockIdx.x << 7;
  int kb = SPLITK ? blockIdx.z * ksplit : 0;
  int ke = SPLITK ? kb + ksplit : K;
  int w = tid >> 6, lane = tid & 63;
  int wm = (w >> 1) << 6, wn = (w & 1) << 6;
  int lm = lane & 15, quad = lane >> 4;
  f32x4 acc[4][4];
  f32x4 z4 = {0.f, 0.f, 0.f, 0.f};
#pragma unroll
  for (int i = 0; i < 4; i++)
#pragma unroll
    for (int j = 0; j < 4; j++) acc[i][j] = z4;

  int srow = tid >> 2;          // 0..63
  int soff = (tid & 3) * 8;     // bf16 elems within K-chunk
  const bf16* Ab  = A + (size_t)(m0 + srow) * K + kb + soff;
  const bf16* Ab2 = Ab + (size_t)64 * K;
  const bf16* Wb  = W + (size_t)(n0 + srow) * K + kb + soff;
  const bf16* Wb2 = Wb + (size_t)64 * K;
  short* AL  = &As[(size_t)tid * 8];
  short* AL2 = &As[(size_t)(tid + 256) * 8];
  short* WL  = &Ws[(size_t)tid * 8];
  short* WL2 = &Ws[(size_t)(tid + 256) * 8];

  for (int k0 = kb; k0 < ke; k0 += 32) {
    load_lds16(Ab, AL);  load_lds16(Ab2, AL2);
    load_lds16(Wb, WL);  load_lds16(Wb2, WL2);
    Ab += 32; Ab2 += 32; Wb += 32; Wb2 += 32;
    __syncthreads();   // vmcnt(0) drain -> LDS valid
    bf16x8 af[4], wf[4];
#pragma unroll
    for (int i = 0; i < 4; i++) af[i] = *(const bf16x8*)&As[(wm + i * 16 + lm) * 32 + quad * 8];
#pragma unroll
    for (int j = 0; j < 4; j++) wf[j] = *(const bf16x8*)&Ws[(wn + j * 16 + lm) * 32 + quad * 8];
#pragma unroll
    for (int i = 0; i < 4; i++)
#pragma unroll
      for (int j = 0; j < 4; j++)
        acc[i][j] = __builtin_amdgcn_mfma_f32_16x16x32_bf16(af[i], wf[j], acc[i][j], 0, 0, 0);
    __syncthreads();   // protect LDS before next overwrite
  }

  if (SPLITK) {
    float* P = (float*)C + (size_t)blockIdx.z * M * N;
#pragma unroll
    for (int i = 0; i < 4; i++)
#pragma unroll
      for (int j = 0; j < 4; j++) {
        int col = n0 + wn + j * 16 + lm;
        int rowb = m0 + wm + i * 16 + quad * 4;
#pragma unroll
        for (int r = 0; r < 4; r++)
          P[(size_t)(rowb + r) * N + col] = acc[i][j][r];
      }
  } else {
#pragma unroll
    for (int i = 0; i < 4; i++)
#pragma unroll
      for (int j = 0; j < 4; j++) {
        int col = n0 + wn + j * 16 + lm;
        int rowb = m0 + wm + i * 16 + quad * 4;
        float bias = (b1 ? b1[col] : 0.f) + (b2 ? b2[col] : 0.f);
#pragma unroll
        for (int r = 0; r < 4; r++) {
          float v = acc[i][j][r] + bias;
          if (RELU) v = fmaxf(v, 0.f);
          C[(size_t)(rowb + r) * ldc + col] = cvt_out<OutT>(v);
        }
      }
  }
}

// ---------------- split-K reduce + bias + relu ----------------
__global__ __launch_bounds__(256) void splitk_reduce(const float* __restrict__ P,
                                                     const float* __restrict__ bias,
                                                     float* __restrict__ out,
                                                     int MN, int N, int ldc, int nz) {
  int i = blockIdx.x * 256 + threadIdx.x;
  if (i >= MN) return;
  int m = i / N, n = i - m * N;
  float s = bias[n];
  for (int z = 0; z < nz; z++) s += P[(size_t)z * MN + i];
  out[(size_t)m * ldc + n] = fmaxf(s, 0.f);
}

// ---------------- batch-parallel persistent LSTM scan (64 steps, 2 LSTMs) ----------------
// grid (32 r-tiles, 2 lstm) = 64 blocks, 256 thr = 4 waves. Each block owns 16 batch rows
// and computes ALL 1280 gate outputs -> zero inter-block deps, no grid sync, no launches.
// h (hi/lo bf16) lives in LDS double-buffered; c in registers; Whh streams from L2
// (800 KB/step/block, L2-resident). Wave w handles hidden cols [w*80, w*80+80).
// FP order identical to the verified per-step kernel (chunk-ascending, hi then lo).
struct ScanArgs {
  const bf16 *xgF, *xgR, *WhhA, *WhhB;
  bf16 *outA, *outB;
  int ldo; size_t ostep;
};

__global__ __launch_bounds__(256, 1) void lstm_scan_batch(ScanArgs a) {
  int lst = blockIdx.y;
  const bf16* Whh = lst ? a.WhhB : a.WhhA;
  const bf16* xgS = lst ? a.xgR : a.xgF;
  bf16* ob        = lst ? a.outB : a.outA;
  int r0 = blockIdx.x << 4;   // 16 batch rows per block

  // h state: [16 rows][328 cols] (pad 320->328 shorts = 656B rows: conflict-free b128 reads)
  __shared__ __align__(16) short Hh[2][16 * 328];
  __shared__ __align__(16) short Hl[2][16 * 328];

  int tid = threadIdx.x;
  int w = tid >> 6, lane = tid & 63;
  int lm = lane & 15, quad = lane >> 4;
  int q8 = quad << 3;
  int jrow_base = (w * 80) + lm;    // Whh col-row base for this lane (plus s*16, g*320)

  // zero-init h buffers (t=0 state), buffer 0
  for (int i = tid; i < 2624; i += 256) {
    ((int*)Hh[0])[i] = 0;
    ((int*)Hl[0])[i] = 0;
  }
  float creg[5][4];
#pragma unroll
  for (int s = 0; s < 5; s++)
#pragma unroll
    for (int r = 0; r < 4; r++) creg[s][r] = 0.f;
  __syncthreads();

  int cur = 0;
  for (int t = 0; t < 64; ++t) {
    const bf16* xg_t = xgS + (size_t)(lst ? (63 - t) : t) * 655360;
    int nxt = cur ^ 1;

    // load A fragments (h hi/lo) for the step: 16 rows x 320 cols, per-lane row lm
    bf16x8 ah[10], al[10];
#pragma unroll
    for (int kk = 0; kk < 10; ++kk) {
      ah[kk] = *(const bf16x8*)&Hh[cur][lm * 328 + kk * 32 + q8];
      al[kk] = *(const bf16x8*)&Hl[cur][lm * 328 + kk * 32 + q8];
    }

#pragma unroll
    for (int s = 0; s < 5; ++s) {
      f32x4 acc[4];
      f32x4 z4 = {0.f, 0.f, 0.f, 0.f};
#pragma unroll
      for (int g = 0; g < 4; ++g) acc[g] = z4;

#pragma unroll
      for (int g = 0; g < 4; ++g) {
        const bf16* wp = Whh + (size_t)(g * 320 + s * 16 + jrow_base) * 320 + q8;
        bf16x8 wf[10];
#pragma unroll
        for (int kk = 0; kk < 10; ++kk)
          wf[kk] = *(const bf16x8*)(wp + kk * 32);
#pragma unroll
        for (int kk = 0; kk < 10; ++kk) {
          acc[g] = __builtin_amdgcn_mfma_f32_16x16x32_bf16(ah[kk], wf[kk], acc[g], 0, 0, 0);
          acc[g] = __builtin_amdgcn_mfma_f32_16x16x32_bf16(al[kk], wf[kk], acc[g], 0, 0, 0);
        }
      }

      // pointwise for this 16-col hidden tile; lane holds col jc, rows quad*4+rr
      int jc = w * 80 + s * 16 + lm;      // hidden col 0..319
#pragma unroll
      for (int rr = 0; rr < 4; ++rr) {
        int lrow = (quad << 2) + rr;
        int row = r0 + lrow;
        const unsigned short* xr = (const unsigned short*)xg_t + (size_t)row * 1280 + jc;
        float p0 = acc[0][rr] + bu2f(xr[0]);
        float p1 = acc[1][rr] + bu2f(xr[320]);
        float p2 = acc[2][rr] + bu2f(xr[640]);
        float p3 = acc[3][rr] + bu2f(xr[960]);
        float iv = sigf(p0), fv = sigf(p1), gv = tanhf(p2), ov = sigf(p3);
        float cn = fv * creg[s][rr] + iv * gv;
        float hn = ov * tanhf(cn);
        creg[s][rr] = cn;
        unsigned short hu = f2bu(hn);
        unsigned short hl = f2bu(hn - bu2f(hu));
        Hh[nxt][lrow * 328 + jc] = (short)hu;
        Hl[nxt][lrow * 328 + jc] = (short)hl;
        ((unsigned short*)ob)[(size_t)t * a.ostep + (size_t)row * a.ldo + jc] = hu;
      }
    }
    __syncthreads();   // all h_next writes visible before next step's reads
    cur = nxt;
  }
}

// ---------------- conv1 (3x3) + relu + maxpool2 fused ----------------
__global__ __launch_bounds__(256) void conv1_pool(
    const float* __restrict__ X, const float* __restrict__ w,
    const float* __restrict__ bias, float* __restrict__ pool) {
  int b = blockIdx.x;
  __shared__ float Xs[3 * 32 * 32];
  __shared__ float Wl[128 * 27];
  __shared__ float Bl[128];
  int tid = threadIdx.x;
  for (int i = tid; i < 3072; i += 256) Xs[i] = X[(size_t)b * 3072 + i];
  for (int i = tid; i < 3456; i += 256) Wl[i] = w[i];
  if (tid < 128) Bl[tid] = bias[tid];
  __syncthreads();
  int oc = tid & 127, half = tid >> 7;
  float wr[27];
#pragma unroll
  for (int q = 0; q < 27; q++) wr[q] = Wl[oc * 27 + q];
  float bv = Bl[oc];
  for (int p = half; p < 225; p += 2) {
    int i = p / 15, j = p % 15;
    float mx = -3.4e38f;
#pragma unroll
    for (int dy = 0; dy < 2; dy++)
#pragma unroll
      for (int dx = 0; dx < 2; dx++) {
        float s = bv;
        int rb = 2 * i + dy, cb = 2 * j + dx;
#pragma unroll
        for (int cc = 0; cc < 3; cc++)
#pragma unroll
          for (int kr = 0; kr < 3; kr++)
#pragma unroll
            for (int kc = 0; kc < 3; kc++)
              s += wr[cc * 9 + kr * 3 + kc] * Xs[cc * 1024 + (rb + kr) * 32 + cb + kc];
        mx = fmaxf(mx, s);
      }
    pool[((size_t)(b * 128 + oc)) * 225 + p] = fmaxf(mx, 0.f);
  }
}

// ---------------- batchnorm stats -> fold to a*x+s ----------------
__global__ void bn_stats(const float* __restrict__ x, int C, int per, int B,
                         const float* __restrict__ g, const float* __restrict__ bb,
                         float* __restrict__ a, float* __restrict__ s) {
  int c = blockIdx.x;
  int n = B * per;
  float sum = 0.f, sq = 0.f;
  for (int i = threadIdx.x; i < n; i += 256) {
    int b = i / per, p = i - b * per;
    float v = x[((size_t)b * C + c) * per + p];
    sum += v; sq += v * v;
  }
  __shared__ float S1[256], S2[256];
  S1[threadIdx.x] = sum; S2[threadIdx.x] = sq;
  __syncthreads();
  for (int off = 128; off > 0; off >>= 1) {
    if (threadIdx.x < off) { S1[threadIdx.x] += S1[threadIdx.x + off]; S2[threadIdx.x] += S2[threadIdx.x + off]; }
    __syncthreads();
  }
  if (threadIdx.x == 0) {
    float m = S1[0] / n;
    float var = S2[0] / n - m * m;
    float av = g[c] * rsqrtf(var + 1e-5f);
    a[c] = av; s[c] = bb[c] - m * av;
  }
}

__global__ void bn_apply_bf16(const float* __restrict__ x, bf16* __restrict__ y,
                              const float* __restrict__ a, const float* __restrict__ s,
                              int per, int C, size_t total) {
  size_t i = (size_t)blockIdx.x * 256 + threadIdx.x;
  if (i < total) {
    int ch = (int)((i / per) % C);
    y[i] = __float2bfloat16(a[ch] * x[i] + s[ch]);
  }
}

// ---------------- conv2 (4x4, 128->48), bn1 on load, relu on store ----------------
__global__ __launch_bounds__(192) void conv2_kernel(
    const float* __restrict__ pool, const float* __restrict__ w,
    const float* __restrict__ bias, const float* __restrict__ a1,
    const float* __restrict__ s1, float* __restrict__ out) {
  int rg = blockIdx.x, b = blockIdx.y;
  int r0 = rg * 4;
  __shared__ float L[128 * 7 * 15];
  int tid = threadIdx.x;
#pragma unroll
  for (int i = 0; i < 70; i++) {
    int idx = tid + i * 192;
    int c = idx / 105, rem = idx % 105;
    int r = rem / 15, col = rem % 15;
    L[idx] = pool[((size_t)(b * 128 + c)) * 225 + (r0 + r) * 15 + col] * a1[c] + s1[c];
  }
  __syncthreads();
  int oc = tid % 48, orow = tid / 48;
  float acc[12];
  float bv = bias[oc];
#pragma unroll
  for (int j = 0; j < 12; j++) acc[j] = bv;
  for (int c = 0; c < 128; c++) {
#pragma unroll
    for (int kr = 0; kr < 4; kr++) {
      float v[15];
#pragma unroll
      for (int q = 0; q < 15; q++) v[q] = L[(c * 7 + orow + kr) * 15 + q];
      const float* wp = &w[((size_t)(oc * 128 + c)) * 16 + kr * 4];
#pragma unroll
      for (int kc = 0; kc < 4; kc++) {
        float wv = wp[kc];
#pragma unroll
        for (int j = 0; j < 12; j++) acc[j] += wv * v[j + kc];
      }
    }
  }
  float* op = &out[((size_t)(b * 48 + oc)) * 144 + (r0 + orow) * 12];
#pragma unroll
  for (int j = 0; j < 12; j++) op[j] = fmaxf(acc[j], 0.f);
}

// ---------------- fc + log_softmax ----------------
__global__ __launch_bounds__(64) void fc_logsoftmax(
    const float* __restrict__ A, const float* __restrict__ W,
    const float* __restrict__ bias, float* __restrict__ out) {
  int b = blockIdx.x, lane = threadIdx.x;
  float acc[10] = {};
  for (int k = lane; k < 4096; k += 64) {
    float x = A[(size_t)b * 4096 + k];
#pragma unroll
    for (int o = 0; o < 10; o++) acc[o] += x * W[o * 4096 + k];
  }
#pragma unroll
  for (int o = 0; o < 10; o++)
    for (int off = 32; off > 0; off >>= 1) acc[o] += __shfl_down(acc[o], off);
  if (lane == 0) {
    float l[10];
    float m = -3.4e38f;
#pragma unroll
    for (int o = 0; o < 10; o++) { l[o] = acc[o] + bias[o]; m = fmaxf(m, l[o]); }
    float se = 0.f;
#pragma unroll
    for (int o = 0; o < 10; o++) se += expf(l[o] - m);
    float ls = logf(se);
#pragma unroll
    for (int o = 0; o < 10; o++) out[b * 10 + o] = l[o] - m - ls;
  }
}

extern "C" void kernel_launch(void* const* d_in, const int* in_sizes, int n_in,
                              void* d_out, int out_size, void* d_ws, size_t ws_size,
                              hipStream_t stream) {
  const float* X    = (const float*)d_in[0];
  const float* c1w  = (const float*)d_in[1];
  const float* c1b  = (const float*)d_in[2];
  const float* bn1g = (const float*)d_in[3];
  const float* bn1b = (const float*)d_in[4];
  const float* c2w  = (const float*)d_in[5];
  const float* c2b  = (const float*)d_in[6];
  const float* bn2g = (const float*)d_in[7];
  const float* bn2b = (const float*)d_in[8];
  const float *Wih[4], *Whh[4], *bih[4], *bhh[4];
  for (int i = 0; i < 4; i++) {
    Wih[i] = (const float*)d_in[9 + 4 * i];
    Whh[i] = (const float*)d_in[10 + 4 * i];
    bih[i] = (const float*)d_in[11 + 4 * i];
    bhh[i] = (const float*)d_in[12 + 4 * i];
  }
  const float* d1w = (const float*)d_in[25];
  const float* d1b = (const float*)d_in[26];
  const float* d2w = (const float*)d_in[27];
  const float* d2b = (const float*)d_in[28];
  const float* fcw = (const float*)d_in[29];
  const float* fcb = (const float*)d_in[30];
  float* out = (float*)d_out;

  // ---- workspace layout (~294 MB) ----
  char* p = (char*)d_ws;
  float* v_fw = (float*)p;  p += (size_t)64 * 512 * 48 * 4;         // 6.3 MB
  char* R = p;              p += (size_t)167772160;                  // xg region (2x 83.9MB)
  bf16* xgA = (bf16*)R;
  bf16* xgB = xgA + (size_t)41943040;
  bf16* h_fw = (bf16*)p;    p += (size_t)64 * 512 * 640 * 2;         // 41.9 MB
  bf16* hfm  = (bf16*)p;    p += (size_t)512 * 40960 * 2;            // 41.9 MB
  bf16* wih3b = (bf16*)p;   p += (size_t)1280 * 640 * 2;
  bf16* wih4b = (bf16*)p;   p += (size_t)1280 * 640 * 2;
  bf16* whhb[4];
  for (int i = 0; i < 4; i++) { whhb[i] = (bf16*)p; p += (size_t)1280 * 320 * 2; }
  float* states = (float*)p; p += (size_t)3932160;                   // (unused now)
  float* P = (float*)p;      p += (size_t)4 * 512 * 2048 * 4;        // 16.8 MB split-K partials
  float* outcat = (float*)p; p += (size_t)512 * 4096 * 4;            // 8.4 MB
  float* bnp = (float*)p;    p += 2048;
  // conv aliases inside R (dead after dense1):
  float* pool   = (float*)R;                                         // 59.0 MB
  float* c2out  = (float*)(R + 58982400);                            // 14.2 MB
  bf16*  c2outb = (bf16*)(R + 58982400 + 14155776);                  // 7.1 MB
  bf16*  d2wb   = (bf16*)(R + 58982400 + 14155776 + 7077888);        // 28.3 MB
  bf16*  d1wb   = (bf16*)R;                                          // 167.8 MB (whole R)
  float* a1 = bnp, *s1 = bnp + 128, *a2 = bnp + 256, *s2 = bnp + 304;
  (void)states;

  // 1) patches + small weight conversions
  patch_kernel<<<6144, 256, 0, stream>>>(X, v_fw);
  for (int i = 0; i < 4; i++)
    cvt_f32_bf16_k<<<400, 256, 0, stream>>>(Whh[i], whhb[i], 102400);
  cvt_f32_bf16_k<<<800, 256, 0, stream>>>(Wih[2], wih3b, 204800);
  cvt_f32_bf16_k<<<800, 256, 0, stream>>>(Wih[3], wih4b, 204800);

  // 2) input projections for LSTM 1/2 (K=48, legacy fp32 gemm, bf16 out)
  gemm_nt<bf16, false><<<dim3(20, 512), 256, 0, stream>>>(v_fw, Wih[0], bih[0], bhh[0], xgA, 32768, 1280, 48, 1280);
  gemm_nt<bf16, false><<<dim3(20, 512), 256, 0, stream>>>(v_fw, Wih[1], bih[1], bhh[1], xgB, 32768, 1280, 48, 1280);

  // 3) phase A scan — batch-parallel persistent kernel (no grid sync, no per-step launches)
  {
    ScanArgs sa;
    sa.xgF = xgA; sa.xgR = xgB; sa.WhhA = whhb[0]; sa.WhhB = whhb[1];
    sa.outA = h_fw; sa.outB = h_fw + 320; sa.ldo = 640; sa.ostep = 327680;
    lstm_scan_batch<<<dim3(32, 2), 256, 0, stream>>>(sa);
  }

  // 4) input projections for LSTM 3/4 (MFMA, overwrite xg region)
  gemm_mfma<bf16, false, false><<<dim3(10, 256, 1), 256, 0, stream>>>(h_fw, wih3b, bih[2], bhh[2], xgA, 32768, 1280, 640, 1280, 0);
  gemm_mfma<bf16, false, false><<<dim3(10, 256, 1), 256, 0, stream>>>(h_fw, wih4b, bih[3], bhh[3], xgB, 32768, 1280, 640, 1280, 0);

  // 5) phase B scan -> hfm
  {
    ScanArgs sb;
    sb.xgF = xgA; sb.xgR = xgB; sb.WhhA = whhb[2]; sb.WhhB = whhb[3];
    sb.outA = hfm; sb.outB = hfm + 320; sb.ldo = 40960; sb.ostep = 640;
    lstm_scan_batch<<<dim3(32, 2), 256, 0, stream>>>(sb);
  }

  // 6) dense1 (split-K=4) -> outcat[:, 0:2048]
  cvt_f32_bf16_k<<<81920, 256, 0, stream>>>(d1w, d1wb, 20971520);
  gemm_mfma<float, false, true><<<dim3(16, 4, 4), 256, 0, stream>>>(hfm, d1wb, nullptr, nullptr, P, 512, 2048, 40960, 2048, 10240);
  splitk_reduce<<<4096, 256, 0, stream>>>(P, d1b, outcat, 1048576, 2048, 4096, 4);

  // 7) conv branch (d1wb dead -> pool/c2out alias R)
  conv1_pool<<<512, 256, 0, stream>>>(X, c1w, c1b, pool);
  bn_stats<<<128, 256, 0, stream>>>(pool, 128, 225, 512, bn1g, bn1b, a1, s1);
  conv2_kernel<<<dim3(3, 512), 192, 0, stream>>>(pool, c2w, c2b, a1, s1, c2out);
  bn_stats<<<48, 256, 0, stream>>>(c2out, 48, 144, 512, bn2g, bn2b, a2, s2);
  bn_apply_bf16<<<13824, 256, 0, stream>>>(c2out, c2outb, a2, s2, 144, 48, (size_t)3538944);

  // 8) dense2 (split-K=4) -> outcat[:, 2048:4096]
  cvt_f32_bf16_k<<<13824, 256, 0, stream>>>(d2w, d2wb, 3538944);
  gemm_mfma<float, false, true><<<dim3(16, 4, 4), 256, 0, stream>>>(c2outb, d2wb, nullptr, nullptr, P, 512, 2048, 6912, 2048, 1728);
  splitk_reduce<<<4096, 256, 0, stream>>>(P, d2b, outcat + 2048, 1048576, 2048, 4096, 4);

  // 9) fc + log_softmax
  fc_logsoftmax<<<512, 64, 0, stream>>>(outcat, fcw, fcb, out);
}

// Round 3
// 5154.256 us; speedup vs baseline: 1.7555x; 1.1838x over previous
//
#include <hip/hip_runtime.h>
#include <hip/hip_bf16.h>
#include <math.h>

typedef __hip_bfloat16 bf16;
typedef short bf16x8 __attribute__((ext_vector_type(8)));   // 8 bf16 = 4 VGPRs
typedef float f32x4 __attribute__((ext_vector_type(4)));

__device__ __forceinline__ float sigf(float x) { return 1.f / (1.f + expf(-x)); }

template<typename T> __device__ __forceinline__ T cvt_out(float v);
template<> __device__ __forceinline__ float cvt_out<float>(float v) { return v; }
template<> __device__ __forceinline__ bf16  cvt_out<bf16>(float v)  { return __float2bfloat16(v); }

__device__ __forceinline__ unsigned short f2bu(float x) {
  bf16 b = __float2bfloat16(x);
  return *reinterpret_cast<unsigned short*>(&b);
}
__device__ __forceinline__ float bu2f(unsigned short u) {
  unsigned int x = ((unsigned int)u) << 16;
  return __uint_as_float(x);
}

// async global->LDS, 16B per lane. LDS dest must be wave-uniform-base + lane*16.
__device__ __forceinline__ void load_lds16(const void* g, void* l) {
  __builtin_amdgcn_global_load_lds(
      (const __attribute__((address_space(1))) unsigned int*)g,
      (__attribute__((address_space(3))) unsigned int*)l,
      16, 0, 0);
}

// ---------------- patch extraction: X[512,3,32,32] -> v_fw[64,512,48] f32 ----------------
__global__ void patch_kernel(const float* __restrict__ X, float* __restrict__ v) {
  int idx = blockIdx.x * 256 + threadIdx.x;
  int k = idx % 48;
  int b = (idx / 48) % 512;
  int t = idx / (48 * 512);
  int c = k >> 4, r = (k >> 2) & 3, s = k & 3;
  int ph = t & 7, pw = t >> 3;
  v[idx] = X[((b * 3 + c) * 32 + ph * 4 + r) * 32 + pw * 4 + s];
}

// ---------------- fp32 -> bf16 convert (x4 vectorized) ----------------
__global__ __launch_bounds__(256) void cvt_f32_bf16_k(const float* __restrict__ in,
                                                      bf16* __restrict__ out, size_t n4) {
  size_t i = (size_t)blockIdx.x * 256 + threadIdx.x;
  if (i >= n4) return;
  float4 v = ((const float4*)in)[i];
  ushort4 o;
  o.x = f2bu(v.x); o.y = f2bu(v.y); o.z = f2bu(v.z); o.w = f2bu(v.w);
  ((ushort4*)out)[i] = o;
}

// ---------------- legacy fp32 GEMM (only for xg1/xg2, K=48): C = A@W^T + b1 + b2 ----------------
template<typename OutT, bool RELU>
__global__ __launch_bounds__(256) void gemm_nt(
    const float* __restrict__ A, const float* __restrict__ W,
    const float* __restrict__ b1, const float* __restrict__ b2,
    OutT* __restrict__ C, int M, int N, int K, int ldc) {
  __shared__ float As[16][68];
  __shared__ float Ws[16][68];
  int tid = threadIdx.x;
  int tx = tid & 15, ty = tid >> 4;
  int m0 = blockIdx.y << 6, n0 = blockIdx.x << 6;
  const float* Ap = A + (size_t)m0 * K;
  const float* Wp = W + (size_t)n0 * K;
  float acc[4][4] = {};
  for (int k0 = 0; k0 < K; k0 += 16) {
#pragma unroll
    for (int i = 0; i < 4; i++) {
      int idx = tid + (i << 8);
      int row = idx >> 4, col = idx & 15;
      As[col][row] = Ap[(size_t)row * K + k0 + col];
      Ws[col][row] = Wp[(size_t)row * K + k0 + col];
    }
    __syncthreads();
#pragma unroll
    for (int kk = 0; kk < 16; kk++) {
      float4 av = *(const float4*)&As[kk][ty << 2];
      float4 wv = *(const float4*)&Ws[kk][tx << 2];
      float a[4] = {av.x, av.y, av.z, av.w};
      float w[4] = {wv.x, wv.y, wv.z, wv.w};
#pragma unroll
      for (int i = 0; i < 4; i++)
#pragma unroll
        for (int j = 0; j < 4; j++) acc[i][j] += a[i] * w[j];
    }
    __syncthreads();
  }
#pragma unroll
  for (int i = 0; i < 4; i++) {
    int m = m0 + (ty << 2) + i;
#pragma unroll
    for (int j = 0; j < 4; j++) {
      int n = n0 + (tx << 2) + j;
      float v = acc[i][j];
      if (b1) v += b1[n];
      if (b2) v += b2[n];
      if (RELU) v = fmaxf(v, 0.f);
      C[(size_t)m * ldc + n] = cvt_out<OutT>(v);
    }
  }
}

// ---------------- bf16 MFMA GEMM (NT): C[M,N] = A[M,K] @ W[N,K]^T (+bias) ----------------
template<typename OutT, bool RELU, bool SPLITK>
__global__ __launch_bounds__(256) void gemm_mfma(
    const bf16* __restrict__ A, const bf16* __restrict__ W,
    const float* __restrict__ b1, const float* __restrict__ b2,
    OutT* __restrict__ C, int M, int N, int K, int ldc, int ksplit) {
  __shared__ __align__(16) short As[128 * 32];
  __shared__ __align__(16) short Ws[128 * 32];
  int tid = threadIdx.x;
  int m0 = blockIdx.y << 7, n0 = blockIdx.x << 7;
  int kb = SPLITK ? blockIdx.z * ksplit : 0;
  int ke = SPLITK ? kb + ksplit : K;
  int w = tid >> 6, lane = tid & 63;
  int wm = (w >> 1) << 6, wn = (w & 1) << 6;
  int lm = lane & 15, quad = lane >> 4;
  f32x4 acc[4][4];
  f32x4 z4 = {0.f, 0.f, 0.f, 0.f};
#pragma unroll
  for (int i = 0; i < 4; i++)
#pragma unroll
    for (int j = 0; j < 4; j++) acc[i][j] = z4;

  int srow = tid >> 2;          // 0..63
  int soff = (tid & 3) * 8;     // bf16 elems within K-chunk
  const bf16* Ab  = A + (size_t)(m0 + srow) * K + kb + soff;
  const bf16* Ab2 = Ab + (size_t)64 * K;
  const bf16* Wb  = W + (size_t)(n0 + srow) * K + kb + soff;
  const bf16* Wb2 = Wb + (size_t)64 * K;
  short* AL  = &As[(size_t)tid * 8];
  short* AL2 = &As[(size_t)(tid + 256) * 8];
  short* WL  = &Ws[(size_t)tid * 8];
  short* WL2 = &Ws[(size_t)(tid + 256) * 8];

  for (int k0 = kb; k0 < ke; k0 += 32) {
    load_lds16(Ab, AL);  load_lds16(Ab2, AL2);
    load_lds16(Wb, WL);  load_lds16(Wb2, WL2);
    Ab += 32; Ab2 += 32; Wb += 32; Wb2 += 32;
    __syncthreads();   // vmcnt(0) drain -> LDS valid
    bf16x8 af[4], wf[4];
#pragma unroll
    for (int i = 0; i < 4; i++) af[i] = *(const bf16x8*)&As[(wm + i * 16 + lm) * 32 + quad * 8];
#pragma unroll
    for (int j = 0; j < 4; j++) wf[j] = *(const bf16x8*)&Ws[(wn + j * 16 + lm) * 32 + quad * 8];
#pragma unroll
    for (int i = 0; i < 4; i++)
#pragma unroll
      for (int j = 0; j < 4; j++)
        acc[i][j] = __builtin_amdgcn_mfma_f32_16x16x32_bf16(af[i], wf[j], acc[i][j], 0, 0, 0);
    __syncthreads();   // protect LDS before next overwrite
  }

  if (SPLITK) {
    float* P = (float*)C + (size_t)blockIdx.z * M * N;
#pragma unroll
    for (int i = 0; i < 4; i++)
#pragma unroll
      for (int j = 0; j < 4; j++) {
        int col = n0 + wn + j * 16 + lm;
        int rowb = m0 + wm + i * 16 + quad * 4;
#pragma unroll
        for (int r = 0; r < 4; r++)
          P[(size_t)(rowb + r) * N + col] = acc[i][j][r];
      }
  } else {
#pragma unroll
    for (int i = 0; i < 4; i++)
#pragma unroll
      for (int j = 0; j < 4; j++) {
        int col = n0 + wn + j * 16 + lm;
        int rowb = m0 + wm + i * 16 + quad * 4;
        float bias = (b1 ? b1[col] : 0.f) + (b2 ? b2[col] : 0.f);
#pragma unroll
        for (int r = 0; r < 4; r++) {
          float v = acc[i][j][r] + bias;
          if (RELU) v = fmaxf(v, 0.f);
          C[(size_t)(rowb + r) * ldc + col] = cvt_out<OutT>(v);
        }
      }
  }
}

// ---------------- split-K reduce + bias + relu ----------------
__global__ __launch_bounds__(256) void splitk_reduce(const float* __restrict__ P,
                                                     const float* __restrict__ bias,
                                                     float* __restrict__ out,
                                                     int MN, int N, int ldc, int nz) {
  int i = blockIdx.x * 256 + threadIdx.x;
  if (i >= MN) return;
  int m = i / N, n = i - m * N;
  float s = bias[n];
  for (int z = 0; z < nz; z++) s += P[(size_t)z * MN + i];
  out[(size_t)m * ldc + n] = fmaxf(s, 0.f);
}

// ---------------- batch-parallel persistent LSTM scan (64 steps, 2 LSTMs) ----------------
// grid (32 r-tiles, 2 lstm) = 64 blocks, 512 thr = 8 waves (2/SIMD for latency hiding).
// Each block owns 16 batch rows, computes ALL 1280 gate outputs -> zero inter-block deps.
// Tiles (20 x 16-col) split 3/3/3/3/2/2/2/2 across waves (waves w,w+4 share a SIMD -> 5/SIMD).
// xg staged to LDS double-buffered via global_load_lds (hidden under gemm); h stays in LDS;
// c in registers; Whh streams from L2. One barrier per step. FP order identical to round 2.
struct ScanArgs {
  const bf16 *xgF, *xgR, *WhhA, *WhhB;
  bf16 *outA, *outB;
  int ldo; size_t ostep;
};

__global__ __launch_bounds__(512, 2) void lstm_scan_batch(ScanArgs a) {
  int lst = blockIdx.y;
  const bf16* Whh = lst ? a.WhhB : a.WhhA;
  const bf16* xgS = lst ? a.xgR : a.xgF;
  bf16* ob        = lst ? a.outB : a.outA;
  int r0 = blockIdx.x << 4;   // 16 batch rows per block

  // h state: [16 rows][328 cols] (pad 320->328 shorts: 2-way-max bank aliasing on b128 reads)
  __shared__ __align__(16) short Hh[2][16 * 328];   // 21.0 KB
  __shared__ __align__(16) short Hl[2][16 * 328];   // 21.0 KB
  __shared__ __align__(16) short XG[2][16 * 1280];  // 80.0 KB (double-buffered xg tile)

  int tid = threadIdx.x;
  int w = tid >> 6, lane = tid & 63;
  int lm = lane & 15, quad = lane >> 4;
  int q8 = quad << 3;

  // tile assignment: waves 0-3 -> 3 tiles, waves 4-7 -> 2 tiles (20 total)
  int ntile = (w < 4) ? 3 : 2;
  int tbase = (w < 4) ? 3 * w : 12 + 2 * (w - 4);

  // zero-init h buffer 0
  for (int i = tid; i < 2624; i += 512) {
    ((int*)Hh[0])[i] = 0;
    ((int*)Hl[0])[i] = 0;
  }
  // stage XG[0] for t=0: 40 KB = 40 segs of 1 KB, 5 per wave
  {
    const char* src = (const char*)(xgS + (size_t)(lst ? 63 : 0) * 655360 + (size_t)r0 * 1280);
#pragma unroll
    for (int i = 0; i < 5; i++) {
      int seg = w * 5 + i;
      load_lds16(src + seg * 1024 + lane * 16, (char*)XG[0] + seg * 1024 + lane * 16);
    }
  }
  float creg[3][4];
#pragma unroll
  for (int s = 0; s < 3; s++)
#pragma unroll
    for (int r = 0; r < 4; r++) creg[s][r] = 0.f;
  __syncthreads();   // drains XG stage (vmcnt 0 before barrier) + h zeros visible

  int cur = 0;
  for (int t = 0; t < 64; ++t) {
    // prefetch next step's xg tile into the other buffer (hidden under gemm)
    if (t < 63) {
      const char* src = (const char*)(xgS + (size_t)(lst ? 62 - t : t + 1) * 655360 + (size_t)r0 * 1280);
      char* dst = (char*)XG[(t + 1) & 1];
#pragma unroll
      for (int i = 0; i < 5; i++) {
        int seg = w * 5 + i;
        load_lds16(src + seg * 1024 + lane * 16, dst + seg * 1024 + lane * 16);
      }
    }

    // load A fragments (h hi/lo): 20 ds_read_b128, reused across all tiles/gates
    bf16x8 ah[10], al[10];
#pragma unroll
    for (int kk = 0; kk < 10; ++kk) {
      ah[kk] = *(const bf16x8*)&Hh[cur][lm * 328 + kk * 32 + q8];
      al[kk] = *(const bf16x8*)&Hl[cur][lm * 328 + kk * 32 + q8];
    }
    const unsigned short* xgl = (const unsigned short*)XG[t & 1];
    int nxt = cur ^ 1;

#pragma unroll
    for (int tt = 0; tt < 3; ++tt) {
      if (tt < ntile) {
        int stile = tbase + tt;
        int jc = (stile << 4) + lm;       // hidden col 0..319
        f32x4 acc[4];
        f32x4 z4 = {0.f, 0.f, 0.f, 0.f};
#pragma unroll
        for (int g = 0; g < 4; ++g) acc[g] = z4;

#pragma unroll
        for (int g = 0; g < 4; ++g) {
          const bf16* wp = Whh + (size_t)(g * 320 + (stile << 4) + lm) * 320 + q8;
          bf16x8 wf[10];
#pragma unroll
          for (int kk = 0; kk < 10; ++kk)
            wf[kk] = *(const bf16x8*)(wp + kk * 32);
#pragma unroll
          for (int kk = 0; kk < 10; ++kk) {
            acc[g] = __builtin_amdgcn_mfma_f32_16x16x32_bf16(ah[kk], wf[kk], acc[g], 0, 0, 0);
            acc[g] = __builtin_amdgcn_mfma_f32_16x16x32_bf16(al[kk], wf[kk], acc[g], 0, 0, 0);
          }
        }

        // pointwise: lane holds col jc, rows quad*4+rr; xg from LDS
#pragma unroll
        for (int rr = 0; rr < 4; ++rr) {
          int lrow = (quad << 2) + rr;
          const unsigned short* xr = xgl + lrow * 1280 + jc;
          float p0 = acc[0][rr] + bu2f(xr[0]);
          float p1 = acc[1][rr] + bu2f(xr[320]);
          float p2 = acc[2][rr] + bu2f(xr[640]);
          float p3 = acc[3][rr] + bu2f(xr[960]);
          float iv = sigf(p0), fv = sigf(p1), gv = tanhf(p2), ov = sigf(p3);
          float cn = fv * creg[tt][rr] + iv * gv;
          float hn = ov * tanhf(cn);
          creg[tt][rr] = cn;
          unsigned short hu = f2bu(hn);
          Hh[nxt][lrow * 328 + jc] = (short)hu;
          Hl[nxt][lrow * 328 + jc] = (short)f2bu(hn - bu2f(hu));
        }
      }
    }
    __syncthreads();   // h_next complete (also drains xg prefetch)

    // coalesced h -> out copy: 640 x 16B segments (rows of 320 cols, 8-col blocks)
    for (int i = tid; i < 640; i += 512) {
      int row = i / 40, cb = (i - row * 40) * 8;
      *(bf16x8*)((unsigned short*)ob + (size_t)t * a.ostep + (size_t)(r0 + row) * a.ldo + cb) =
          *(const bf16x8*)&Hh[nxt][row * 328 + cb];
    }
    cur = nxt;
  }
}

// ---------------- conv1 (3x3) + relu + maxpool2 fused ----------------
__global__ __launch_bounds__(256) void conv1_pool(
    const float* __restrict__ X, const float* __restrict__ w,
    const float* __restrict__ bias, float* __restrict__ pool) {
  int b = blockIdx.x;
  __shared__ float Xs[3 * 32 * 32];
  __shared__ float Wl[128 * 27];
  __shared__ float Bl[128];
  int tid = threadIdx.x;
  for (int i = tid; i < 3072; i += 256) Xs[i] = X[(size_t)b * 3072 + i];
  for (int i = tid; i < 3456; i += 256) Wl[i] = w[i];
  if (tid < 128) Bl[tid] = bias[tid];
  __syncthreads();
  int oc = tid & 127, half = tid >> 7;
  float wr[27];
#pragma unroll
  for (int q = 0; q < 27; q++) wr[q] = Wl[oc * 27 + q];
  float bv = Bl[oc];
  for (int p = half; p < 225; p += 2) {
    int i = p / 15, j = p % 15;
    float mx = -3.4e38f;
#pragma unroll
    for (int dy = 0; dy < 2; dy++)
#pragma unroll
      for (int dx = 0; dx < 2; dx++) {
        float s = bv;
        int rb = 2 * i + dy, cb = 2 * j + dx;
#pragma unroll
        for (int cc = 0; cc < 3; cc++)
#pragma unroll
          for (int kr = 0; kr < 3; kr++)
#pragma unroll
            for (int kc = 0; kc < 3; kc++)
              s += wr[cc * 9 + kr * 3 + kc] * Xs[cc * 1024 + (rb + kr) * 32 + cb + kc];
        mx = fmaxf(mx, s);
      }
    pool[((size_t)(b * 128 + oc)) * 225 + p] = fmaxf(mx, 0.f);
  }
}

// ---------------- batchnorm stats -> fold to a*x+s ----------------
__global__ void bn_stats(const float* __restrict__ x, int C, int per, int B,
                         const float* __restrict__ g, const float* __restrict__ bb,
                         float* __restrict__ a, float* __restrict__ s) {
  int c = blockIdx.x;
  int n = B * per;
  float sum = 0.f, sq = 0.f;
  for (int i = threadIdx.x; i < n; i += 256) {
    int b = i / per, p = i - b * per;
    float v = x[((size_t)b * C + c) * per + p];
    sum += v; sq += v * v;
  }
  __shared__ float S1[256], S2[256];
  S1[threadIdx.x] = sum; S2[threadIdx.x] = sq;
  __syncthreads();
  for (int off = 128; off > 0; off >>= 1) {
    if (threadIdx.x < off) { S1[threadIdx.x] += S1[threadIdx.x + off]; S2[threadIdx.x] += S2[threadIdx.x + off]; }
    __syncthreads();
  }
  if (threadIdx.x == 0) {
    float m = S1[0] / n;
    float var = S2[0] / n - m * m;
    float av = g[c] * rsqrtf(var + 1e-5f);
    a[c] = av; s[c] = bb[c] - m * av;
  }
}

__global__ void bn_apply_bf16(const float* __restrict__ x, bf16* __restrict__ y,
                              const float* __restrict__ a, const float* __restrict__ s,
                              int per, int C, size_t total) {
  size_t i = (size_t)blockIdx.x * 256 + threadIdx.x;
  if (i < total) {
    int ch = (int)((i / per) % C);
    y[i] = __float2bfloat16(a[ch] * x[i] + s[ch]);
  }
}

// ---------------- conv2 (4x4, 128->48), bn1 on load, relu on store ----------------
__global__ __launch_bounds__(192) void conv2_kernel(
    const float* __restrict__ pool, const float* __restrict__ w,
    const float* __restrict__ bias, const float* __restrict__ a1,
    const float* __restrict__ s1, float* __restrict__ out) {
  int rg = blockIdx.x, b = blockIdx.y;
  int r0 = rg * 4;
  __shared__ float L[128 * 7 * 15];
  int tid = threadIdx.x;
#pragma unroll
  for (int i = 0; i < 70; i++) {
    int idx = tid + i * 192;
    int c = idx / 105, rem = idx % 105;
    int r = rem / 15, col = rem % 15;
    L[idx] = pool[((size_t)(b * 128 + c)) * 225 + (r0 + r) * 15 + col] * a1[c] + s1[c];
  }
  __syncthreads();
  int oc = tid % 48, orow = tid / 48;
  float acc[12];
  float bv = bias[oc];
#pragma unroll
  for (int j = 0; j < 12; j++) acc[j] = bv;
  for (int c = 0; c < 128; c++) {
#pragma unroll
    for (int kr = 0; kr < 4; kr++) {
      float v[15];
#pragma unroll
      for (int q = 0; q < 15; q++) v[q] = L[(c * 7 + orow + kr) * 15 + q];
      const float* wp = &w[((size_t)(oc * 128 + c)) * 16 + kr * 4];
#pragma unroll
      for (int kc = 0; kc < 4; kc++) {
        float wv = wp[kc];
#pragma unroll
        for (int j = 0; j < 12; j++) acc[j] += wv * v[j + kc];
      }
    }
  }
  float* op = &out[((size_t)(b * 48 + oc)) * 144 + (r0 + orow) * 12];
#pragma unroll
  for (int j = 0; j < 12; j++) op[j] = fmaxf(acc[j], 0.f);
}

// ---------------- fc + log_softmax ----------------
__global__ __launch_bounds__(64) void fc_logsoftmax(
    const float* __restrict__ A, const float* __restrict__ W,
    const float* __restrict__ bias, float* __restrict__ out) {
  int b = blockIdx.x, lane = threadIdx.x;
  float acc[10] = {};
  for (int k = lane; k < 4096; k += 64) {
    float x = A[(size_t)b * 4096 + k];
#pragma unroll
    for (int o = 0; o < 10; o++) acc[o] += x * W[o * 4096 + k];
  }
#pragma unroll
  for (int o = 0; o < 10; o++)
    for (int off = 32; off > 0; off >>= 1) acc[o] += __shfl_down(acc[o], off);
  if (lane == 0) {
    float l[10];
    float m = -3.4e38f;
#pragma unroll
    for (int o = 0; o < 10; o++) { l[o] = acc[o] + bias[o]; m = fmaxf(m, l[o]); }
    float se = 0.f;
#pragma unroll
    for (int o = 0; o < 10; o++) se += expf(l[o] - m);
    float ls = logf(se);
#pragma unroll
    for (int o = 0; o < 10; o++) out[b * 10 + o] = l[o] - m - ls;
  }
}

extern "C" void kernel_launch(void* const* d_in, const int* in_sizes, int n_in,
                              void* d_out, int out_size, void* d_ws, size_t ws_size,
                              hipStream_t stream) {
  const float* X    = (const float*)d_in[0];
  const float* c1w  = (const float*)d_in[1];
  const float* c1b  = (const float*)d_in[2];
  const float* bn1g = (const float*)d_in[3];
  const float* bn1b = (const float*)d_in[4];
  const float* c2w  = (const float*)d_in[5];
  const float* c2b  = (const float*)d_in[6];
  const float* bn2g = (const float*)d_in[7];
  const float* bn2b = (const float*)d_in[8];
  const float *Wih[4], *Whh[4], *bih[4], *bhh[4];
  for (int i = 0; i < 4; i++) {
    Wih[i] = (const float*)d_in[9 + 4 * i];
    Whh[i] = (const float*)d_in[10 + 4 * i];
    bih[i] = (const float*)d_in[11 + 4 * i];
    bhh[i] = (const float*)d_in[12 + 4 * i];
  }
  const float* d1w = (const float*)d_in[25];
  const float* d1b = (const float*)d_in[26];
  const float* d2w = (const float*)d_in[27];
  const float* d2b = (const float*)d_in[28];
  const float* fcw = (const float*)d_in[29];
  const float* fcb = (const float*)d_in[30];
  float* out = (float*)d_out;

  // ---- workspace layout (~294 MB) ----
  char* p = (char*)d_ws;
  float* v_fw = (float*)p;  p += (size_t)64 * 512 * 48 * 4;         // 6.3 MB
  char* R = p;              p += (size_t)167772160;                  // xg region (2x 83.9MB)
  bf16* xgA = (bf16*)R;
  bf16* xgB = xgA + (size_t)41943040;
  bf16* h_fw = (bf16*)p;    p += (size_t)64 * 512 * 640 * 2;         // 41.9 MB
  bf16* hfm  = (bf16*)p;    p += (size_t)512 * 40960 * 2;            // 41.9 MB
  bf16* wih3b = (bf16*)p;   p += (size_t)1280 * 640 * 2;
  bf16* wih4b = (bf16*)p;   p += (size_t)1280 * 640 * 2;
  bf16* whhb[4];
  for (int i = 0; i < 4; i++) { whhb[i] = (bf16*)p; p += (size_t)1280 * 320 * 2; }
  float* states = (float*)p; p += (size_t)3932160;                   // (unused now)
  float* P = (float*)p;      p += (size_t)4 * 512 * 2048 * 4;        // 16.8 MB split-K partials
  float* outcat = (float*)p; p += (size_t)512 * 4096 * 4;            // 8.4 MB
  float* bnp = (float*)p;    p += 2048;
  // conv aliases inside R (dead after dense1):
  float* pool   = (float*)R;                                         // 59.0 MB
  float* c2out  = (float*)(R + 58982400);                            // 14.2 MB
  bf16*  c2outb = (bf16*)(R + 58982400 + 14155776);                  // 7.1 MB
  bf16*  d2wb   = (bf16*)(R + 58982400 + 14155776 + 7077888);        // 28.3 MB
  bf16*  d1wb   = (bf16*)R;                                          // 167.8 MB (whole R)
  float* a1 = bnp, *s1 = bnp + 128, *a2 = bnp + 256, *s2 = bnp + 304;
  (void)states;

  // 1) patches + small weight conversions
  patch_kernel<<<6144, 256, 0, stream>>>(X, v_fw);
  for (int i = 0; i < 4; i++)
    cvt_f32_bf16_k<<<400, 256, 0, stream>>>(Whh[i], whhb[i], 102400);
  cvt_f32_bf16_k<<<800, 256, 0, stream>>>(Wih[2], wih3b, 204800);
  cvt_f32_bf16_k<<<800, 256, 0, stream>>>(Wih[3], wih4b, 204800);

  // 2) input projections for LSTM 1/2 (K=48, legacy fp32 gemm, bf16 out)
  gemm_nt<bf16, false><<<dim3(20, 512), 256, 0, stream>>>(v_fw, Wih[0], bih[0], bhh[0], xgA, 32768, 1280, 48, 1280);
  gemm_nt<bf16, false><<<dim3(20, 512), 256, 0, stream>>>(v_fw, Wih[1], bih[1], bhh[1], xgB, 32768, 1280, 48, 1280);

  // 3) phase A scan — batch-parallel persistent kernel (8 waves, xg LDS-staged)
  {
    ScanArgs sa;
    sa.xgF = xgA; sa.xgR = xgB; sa.WhhA = whhb[0]; sa.WhhB = whhb[1];
    sa.outA = h_fw; sa.outB = h_fw + 320; sa.ldo = 640; sa.ostep = 327680;
    lstm_scan_batch<<<dim3(32, 2), 512, 0, stream>>>(sa);
  }

  // 4) input projections for LSTM 3/4 (MFMA, overwrite xg region)
  gemm_mfma<bf16, false, false><<<dim3(10, 256, 1), 256, 0, stream>>>(h_fw, wih3b, bih[2], bhh[2], xgA, 32768, 1280, 640, 1280, 0);
  gemm_mfma<bf16, false, false><<<dim3(10, 256, 1), 256, 0, stream>>>(h_fw, wih4b, bih[3], bhh[3], xgB, 32768, 1280, 640, 1280, 0);

  // 5) phase B scan -> hfm
  {
    ScanArgs sb;
    sb.xgF = xgA; sb.xgR = xgB; sb.WhhA = whhb[2]; sb.WhhB = whhb[3];
    sb.outA = hfm; sb.outB = hfm + 320; sb.ldo = 40960; sb.ostep = 640;
    lstm_scan_batch<<<dim3(32, 2), 512, 0, stream>>>(sb);
  }

  // 6) dense1 (split-K=4) -> outcat[:, 0:2048]
  cvt_f32_bf16_k<<<81920, 256, 0, stream>>>(d1w, d1wb, 20971520);
  gemm_mfma<float, false, true><<<dim3(16, 4, 4), 256, 0, stream>>>(hfm, d1wb, nullptr, nullptr, P, 512, 2048, 40960, 2048, 10240);
  splitk_reduce<<<4096, 256, 0, stream>>>(P, d1b, outcat, 1048576, 2048, 4096, 4);

  // 7) conv branch (d1wb dead -> pool/c2out alias R)
  conv1_pool<<<512, 256, 0, stream>>>(X, c1w, c1b, pool);
  bn_stats<<<128, 256, 0, stream>>>(pool, 128, 225, 512, bn1g, bn1b, a1, s1);
  conv2_kernel<<<dim3(3, 512), 192, 0, stream>>>(pool, c2w, c2b, a1, s1, c2out);
  bn_stats<<<48, 256, 0, stream>>>(c2out, 48, 144, 512, bn2g, bn2b, a2, s2);
  bn_apply_bf16<<<13824, 256, 0, stream>>>(c2out, c2outb, a2, s2, 144, 48, (size_t)3538944);

  // 8) dense2 (split-K=4) -> outcat[:, 2048:4096]
  cvt_f32_bf16_k<<<13824, 256, 0, stream>>>(d2w, d2wb, 3538944);
  gemm_mfma<float, false, true><<<dim3(16, 4, 4), 256, 0, stream>>>(c2outb, d2wb, nullptr, nullptr, P, 512, 2048, 6912, 2048, 1728);
  splitk_reduce<<<4096, 256, 0, stream>>>(P, d2b, outcat + 2048, 1048576, 2048, 4096, 4);

  // 9) fc + log_softmax
  fc_logsoftmax<<<512, 64, 0, stream>>>(outcat, fcw, fcb, out);
}